// Round 19
// baseline (558.793 us; speedup 1.0000x reference)
//
#include <hip/hip_runtime.h>
#include <hip/hip_bf16.h>

// AKT forward, round 19: (1) cvt_all_weights -> 32 elems/thread with batched
// loads; (2) attn KVBLK=128 (8 barrier-drains instead of 16, LDS 64KB,
// per-db V loads to bound VGPR). GEMMs identical to r18 (546us cfg).
//   - glo term dropped (softmax-invariant per-query constant)
//   - pos_key folded into k-GEMM epilogue
// Workspace (~100 MB): Xc 8M | X,Qb,Kp,Vp 4M | Wall 26M elems

#define B_ 4
#define S_ 1024
#define E_ 1024
#define H_ 16
#define D_ 64
#define L_ 4
#define M_ (B_ * S_)  // 4096
#define EE (E_ * E_)  // 1M

typedef __attribute__((ext_vector_type(8))) __bf16 bf16x8;
typedef __attribute__((ext_vector_type(4))) __bf16 bf16x4;
typedef __attribute__((ext_vector_type(4))) float f32x4;
typedef __attribute__((ext_vector_type(8))) unsigned short u16x8;

__device__ __forceinline__ float bf2f(unsigned short u) {
    union { unsigned int i; float f; } x;
    x.i = ((unsigned int)u) << 16;
    return x.f;
}
__device__ __forceinline__ float gelu_exact(float x) {
    return 0.5f * x * (1.0f + erff(x * 0.70710678118654752f));
}
__device__ __forceinline__ bf16x8 pack8(const float4 a, const float4 b) {
    bf16x8 o;
    o[0] = (__bf16)a.x; o[1] = (__bf16)a.y; o[2] = (__bf16)a.z; o[3] = (__bf16)a.w;
    o[4] = (__bf16)b.x; o[5] = (__bf16)b.y; o[6] = (__bf16)b.z; o[7] = (__bf16)b.w;
    return o;
}

// Packed K layout: frag=((bh*16+kt)*4+kb)*2+kc, elem=lane*8+j.
__device__ __forceinline__ size_t kpack_idx(int m, int col) {
    const int b = m >> 10, srow = m & (S_ - 1);
    const int h = col >> 6, d = col & 63;
    const int bh = b * H_ + h;
    const int kt = srow >> 6, kb = (srow >> 4) & 3, l15 = srow & 15;
    const int kc = d >> 5, lhi = (d >> 3) & 3, j = d & 7;
    const int frag = ((bh * 16 + kt) * 4 + kb) * 2 + kc;
    return (size_t)frag * 512 + (size_t)(lhi * 16 + l15) * 8 + j;
}
// Packed V layout (key-permuted to match P^T B-fragments).
__device__ __forceinline__ size_t vpack_idx(int m, int col) {
    const int b = m >> 10, key = m & (S_ - 1);
    const int h = col >> 6, d = col & 63;
    const int bh = b * H_ + h;
    const int kt = key >> 6;
    const int k6 = key & 63;
    const int kc = k6 >> 5, kl = k6 & 31;
    const int lhi = (kl >> 2) & 3;
    const int j = ((kl >> 4) << 2) | (kl & 3);
    const int db = d >> 4, l15 = d & 15;
    const int frag = ((bh * 16 + kt) * 4 + db) * 2 + kc;
    return (size_t)frag * 512 + (size_t)(lhi * 16 + l15) * 8 + j;
}

// ---------------------------------------------------------------------------
// ALL weights -> bf16, 32 elems/thread, loads batched before stores.
// blockIdx.y in [0,26): y<24 -> layer weights; y>=24 -> W_in half.
// ---------------------------------------------------------------------------
__global__ __launch_bounds__(256) void cvt_all_weights(
    const float* __restrict__ Wq, const float* __restrict__ Wk,
    const float* __restrict__ Wv, const float* __restrict__ Wl,
    const float* __restrict__ Win, __bf16* __restrict__ out) {
    const int y = blockIdx.y;  // 0..25
    const int off = (blockIdx.x * 256 + threadIdx.x) * 32;  // < EE
    const float* src;
    if (y >= 24) {
        src = Win + (size_t)(y - 24) * EE + off;
    } else {
        const int l = y / 6, mat = y - l * 6;
        src = (mat == 0) ? Wq + (size_t)l * EE + off
            : (mat == 1) ? Wk + (size_t)l * EE + off
            : (mat == 2) ? Wv + (size_t)l * EE + off
                         : Wl + ((size_t)l * 3 + (mat - 3)) * EE + off;
    }
    __bf16* dst = out + (size_t)y * EE + off;
    float4 a[4], b[4];
#pragma unroll
    for (int h = 0; h < 4; ++h) {
        a[h] = *(const float4*)(src + h * 8);
        b[h] = *(const float4*)(src + h * 8 + 4);
    }
#pragma unroll
    for (int h = 0; h < 4; ++h)
        *(bf16x8*)(dst + h * 8) = pack8(a[h], b[h]);
}

// ---------------------------------------------------------------------------
// Xc[r, 0:2048] = bf16(concat(emb_item[item_idx[r]], emb_skill[skill_idx[r]]))
// ---------------------------------------------------------------------------
__global__ __launch_bounds__(256) void embed_gather(
    const int* __restrict__ item_idx, const int* __restrict__ skill_idx,
    const float* __restrict__ emb_item, const float* __restrict__ emb_skill,
    __bf16* __restrict__ Xc) {
    const int r = blockIdx.x;
    const int c = threadIdx.x * 8;
    const float* s = (c < E_) ? emb_item + (size_t)item_idx[r] * E_ + c
                              : emb_skill + (size_t)skill_idx[r] * E_ + (c - E_);
    const float4 a = *(const float4*)s;
    const float4 b = *(const float4*)(s + 4);
    *(bf16x8*)(Xc + (size_t)r * 2048 + c) = pack8(a, b);
}

// ---------------------------------------------------------------------------
// 64x64-tile GEMM, BK=128: C = A[M_,K]bf16 * Bm[1024,K]^T + bias.
// PACK: 0 = row-major C (+opt GELU); 1 = K-fragment-pack (+pe); 2 = V-pack.
// Grid (16, 64) = 1024 blocks = 4/CU. LDS 32 KB/block.
// ---------------------------------------------------------------------------
template <int ACT, int PACK>
__global__ __launch_bounds__(256) void gemm64(
    const __bf16* __restrict__ A, const __bf16* __restrict__ Bm,
    const float* __restrict__ bias, __bf16* __restrict__ C, int K,
    const float* __restrict__ pe) {
    __shared__ __bf16 As[64 * 128];  // 16 KB
    __shared__ __bf16 Bs[64 * 128];  // 16 KB
    const int tid = threadIdx.x;
    const int lane = tid & 63;
    const int wid = tid >> 6;
    const int wm = wid >> 1;
    const int wn = wid & 1;
    const int l15 = lane & 15, lhi = lane >> 4;

    const int gx = gridDim.x;  // 16
    const int id = blockIdx.y * gx + blockIdx.x;
    const int nwg = gx * gridDim.y;
    const int swz = (id & 7) * (nwg >> 3) + (id >> 3);
    const int m0 = (swz / gx) * 64;
    const int n0 = (swz % gx) * 64;

    const __bf16* pa[4];
    __bf16* la[4];
    const __bf16* pb[4];
    __bf16* lb[4];
#pragma unroll
    for (int j = 0; j < 4; ++j) {
        const int c = wid * 256 + j * 64 + lane;
        const int row = c >> 4, ch = c & 15;
        pa[j] = A + (size_t)(m0 + row) * K + ((ch ^ (row & 15)) << 3);
        la[j] = As + (size_t)c * 8;
        pb[j] = Bm + (size_t)(n0 + row) * K + ((ch ^ (row & 15)) << 3);
        lb[j] = Bs + (size_t)c * 8;
    }

    int aoff[2][4], boff[2][4];
#pragma unroll
    for (int mi = 0; mi < 2; ++mi) {
        const int row = wm * 32 + mi * 16 + l15;
#pragma unroll
        for (int kc = 0; kc < 4; ++kc)
            aoff[mi][kc] = row * 128 + (((kc * 4 + lhi) ^ (row & 15)) << 3);
    }
#pragma unroll
    for (int ni = 0; ni < 2; ++ni) {
        const int row = wn * 32 + ni * 16 + l15;
#pragma unroll
        for (int kc = 0; kc < 4; ++kc)
            boff[ni][kc] = row * 128 + (((kc * 4 + lhi) ^ (row & 15)) << 3);
    }

    f32x4 acc[2][2] = {};

    for (int k0 = 0; k0 < K; k0 += 128) {
#pragma unroll
        for (int j = 0; j < 4; ++j) {
            __builtin_amdgcn_global_load_lds(
                (const __attribute__((address_space(1))) unsigned int*)(pa[j] + k0),
                (__attribute__((address_space(3))) unsigned int*)la[j], 16, 0, 0);
            __builtin_amdgcn_global_load_lds(
                (const __attribute__((address_space(1))) unsigned int*)(pb[j] + k0),
                (__attribute__((address_space(3))) unsigned int*)lb[j], 16, 0, 0);
        }
        __syncthreads();
        bf16x8 af[2][4], bfr[2][4];
#pragma unroll
        for (int mi = 0; mi < 2; ++mi)
#pragma unroll
            for (int kc = 0; kc < 4; ++kc)
                af[mi][kc] = *(const bf16x8*)(As + aoff[mi][kc]);
#pragma unroll
        for (int ni = 0; ni < 2; ++ni)
#pragma unroll
            for (int kc = 0; kc < 4; ++kc)
                bfr[ni][kc] = *(const bf16x8*)(Bs + boff[ni][kc]);
#pragma unroll
        for (int mi = 0; mi < 2; ++mi)
#pragma unroll
            for (int ni = 0; ni < 2; ++ni)
#pragma unroll
                for (int kc = 0; kc < 4; ++kc)
                    acc[mi][ni] = __builtin_amdgcn_mfma_f32_16x16x32_bf16(
                        af[mi][kc], bfr[ni][kc], acc[mi][ni], 0, 0, 0);
        __syncthreads();
    }

    const int ccol0 = n0 + wn * 32 + l15;
    const int crow0 = m0 + wm * 32 + (lhi << 2);
#pragma unroll
    for (int mi = 0; mi < 2; ++mi) {
#pragma unroll
        for (int ni = 0; ni < 2; ++ni) {
            const int col = ccol0 + ni * 16;
            const float bsum = bias[col];
#pragma unroll
            for (int r = 0; r < 4; ++r) {
                const int row = crow0 + mi * 16 + r;
                float v = acc[mi][ni][r] + bsum;
                if (PACK == 0) {
                    if (ACT) v = gelu_exact(v);
                    C[(size_t)row * E_ + col] = (__bf16)v;
                } else if (PACK == 1) {
                    v += pe[((row & (S_ - 1)) << 6) + (col & (D_ - 1))];
                    C[kpack_idx(row, col)] = (__bf16)v;
                } else {
                    C[vpack_idx(row, col)] = (__bf16)v;
                }
            }
        }
    }
}

// ---------------------------------------------------------------------------
// Swapped-QK MFMA flash attention, KVBLK=128 (two 64-key fragment groups per
// phase; 8 barrier-drains). LDS 64 KB, 8 waves, 2 blocks/CU.
// ---------------------------------------------------------------------------
__global__ __launch_bounds__(512) void attn_mfma(
    const __bf16* __restrict__ Q, const __bf16* __restrict__ Kp,
    const __bf16* __restrict__ Vp, __bf16* __restrict__ O) {
    __shared__ __bf16 Slds[2][2][16 * 512];  // [buf][K/V][frag*512] = 64 KB
    const int tid = threadIdx.x;
    const int lane = tid & 63;
    const int w = tid >> 6;
    const int l15 = lane & 15, lhi = lane >> 4;

    const int id = blockIdx.y * gridDim.x + blockIdx.x;  // 0..511
    const int swz = (id & 7) * 64 + (id >> 3);
    const int q0 = (swz & 7) * 128 + w * 16;
    const int bh = swz >> 3;
    const int bb = bh >> 4, hh = bh & 15;

    bf16x8 qf[2];
    {
        const __bf16* qrow =
            Q + (size_t)(bb * S_ + q0 + l15) * E_ + hh * 64 + lhi * 8;
#pragma unroll
        for (int kc = 0; kc < 2; ++kc) {
            const u16x8 raw = *(const u16x8*)(qrow + kc * 32);
            bf16x8 v;
#pragma unroll
            for (int j = 0; j < 8; ++j) v[j] = (__bf16)(bf2f(raw[j]) * 0.125f);
            qf[kc] = v;
        }
    }

    // wave w stages fragments 2w, 2w+1 (of 16) for K and V per 128-tile
    const __bf16* kpw = Kp + ((size_t)bh * 16 * 8 + w * 2) * 512 + lane * 8;
    const __bf16* vpw = Vp + ((size_t)bh * 16 * 8 + w * 2) * 512 + lane * 8;

    float m_l = -1e30f, l_l = 0.f;
    f32x4 oacc[4] = {};

    // prologue: stage tile 0 into buf 0 (4 loads/wave)
#pragma unroll
    for (int f = 0; f < 2; ++f) {
        __builtin_amdgcn_global_load_lds(
            (const __attribute__((address_space(1))) unsigned int*)(kpw + f * 512),
            (__attribute__((address_space(3))) unsigned int*)(
                &Slds[0][0][(w * 2 + f) * 512]), 16, 0, 0);
        __builtin_amdgcn_global_load_lds(
            (const __attribute__((address_space(1))) unsigned int*)(vpw + f * 512),
            (__attribute__((address_space(3))) unsigned int*)(
                &Slds[0][1][(w * 2 + f) * 512]), 16, 0, 0);
    }

    for (int t = 0; t < S_ / 128; ++t) {
        const int cur = t & 1;
        __syncthreads();  // drains vmcnt: buf[cur] ready
        if (t < S_ / 128 - 1) {
            const size_t fo = (size_t)(t + 1) * 16 * 512;
#pragma unroll
            for (int f = 0; f < 2; ++f) {
                __builtin_amdgcn_global_load_lds(
                    (const __attribute__((address_space(1))) unsigned int*)(
                        kpw + fo + f * 512),
                    (__attribute__((address_space(3))) unsigned int*)(
                        &Slds[cur ^ 1][0][(w * 2 + f) * 512]), 16, 0, 0);
                __builtin_amdgcn_global_load_lds(
                    (const __attribute__((address_space(1))) unsigned int*)(
                        vpw + fo + f * 512),
                    (__attribute__((address_space(3))) unsigned int*)(
                        &Slds[cur ^ 1][1][(w * 2 + f) * 512]), 16, 0, 0);
            }
        }
        const __bf16* kl = &Slds[cur][0][0];
        const __bf16* vl = &Slds[cur][1][0];
        // S^T over 128 keys: kb = 0..7, frag = (kb>>2)*8 + (kb&3)*2 + kc
        f32x4 s[8];
#pragma unroll
        for (int kb = 0; kb < 8; ++kb) {
            const int fb = ((kb >> 2) * 8 + (kb & 3) * 2);
            const bf16x8 k0 = *(const bf16x8*)(kl + (fb + 0) * 512 + lane * 8);
            const bf16x8 k1 = *(const bf16x8*)(kl + (fb + 1) * 512 + lane * 8);
            f32x4 z = {};
            z = __builtin_amdgcn_mfma_f32_16x16x32_bf16(k0, qf[0], z, 0, 0, 0);
            s[kb] = __builtin_amdgcn_mfma_f32_16x16x32_bf16(k1, qf[1], z, 0, 0, 0);
        }
        // lane-local softmax over 32 in-lane scores + 2-shfl cross-group
        float mx = fmaxf(fmaxf(s[0][0], s[0][1]), fmaxf(s[0][2], s[0][3]));
#pragma unroll
        for (int kb = 1; kb < 8; ++kb) {
            mx = fmaxf(mx, fmaxf(fmaxf(s[kb][0], s[kb][1]),
                                 fmaxf(s[kb][2], s[kb][3])));
        }
        mx = fmaxf(mx, __shfl_xor(mx, 16));
        mx = fmaxf(mx, __shfl_xor(mx, 32));
        const float mnew = fmaxf(m_l, mx);
        const float corr = __expf(m_l - mnew);
        float p[8][4];
        float rs = 0.f;
#pragma unroll
        for (int kb = 0; kb < 8; ++kb) {
            float sb = 0.f;
#pragma unroll
            for (int r = 0; r < 4; ++r) {
                p[kb][r] = __expf(s[kb][r] - mnew);
                sb += p[kb][r];
            }
            rs += sb;
        }
        rs += __shfl_xor(rs, 16);
        rs += __shfl_xor(rs, 32);
        l_l = l_l * corr + rs;
        m_l = mnew;
#pragma unroll
        for (int db = 0; db < 4; ++db)
#pragma unroll
            for (int r = 0; r < 4; ++r) oacc[db][r] *= corr;
        // pack P^T into B-fragments: pf[kcc] covers keys kcc*32..kcc*32+31
        bf16x8 pf[4];
#pragma unroll
        for (int kcc = 0; kcc < 4; ++kcc) {
            bf16x8 v;
#pragma unroll
            for (int r = 0; r < 4; ++r) {
                v[r] = (__bf16)p[kcc * 2][r];
                v[r + 4] = (__bf16)p[kcc * 2 + 1][r];
            }
            pf[kcc] = v;
        }
        // PV: vf frag for (db,kcc) at ((kcc>>1)*8 + db*2 + (kcc&1))*512
#pragma unroll
        for (int db = 0; db < 4; ++db) {
#pragma unroll
            for (int kcc = 0; kcc < 4; ++kcc) {
                const bf16x8 vv = *(const bf16x8*)(
                    vl + (((kcc >> 1) * 8 + db * 2 + (kcc & 1))) * 512 + lane * 8);
                oacc[db] = __builtin_amdgcn_mfma_f32_16x16x32_bf16(
                    vv, pf[kcc], oacc[db], 0, 0, 0);
            }
        }
    }
    const float inv_l = 1.f / l_l;
    __bf16* orow = O + (size_t)(bb * S_ + q0 + l15) * E_ + hh * 64 + lhi * 4;
#pragma unroll
    for (int db = 0; db < 4; ++db) {
        bf16x4 ov;
#pragma unroll
        for (int r = 0; r < 4; ++r) ov[r] = (__bf16)(oacc[db][r] * inv_l);
        *(bf16x4*)(orow + db * 16) = ov;
    }
}

// ---------------------------------------------------------------------------
// out[m] = bf16 x[m,:] . f32 W_out + b_out -> f32. One wave per row.
// ---------------------------------------------------------------------------
__global__ __launch_bounds__(256) void final_proj(
    const __bf16* __restrict__ X, const float* __restrict__ Wout,
    const float* __restrict__ bout, float* __restrict__ out) {
    const int wid = threadIdx.x >> 6, lane = threadIdx.x & 63;
    const int m = blockIdx.x * 4 + wid;
    const __bf16* xrow = X + (size_t)m * E_;
    float acc = 0.f;
#pragma unroll
    for (int c = 0; c < 2; ++c) {
        const int idx = c * 512 + lane * 8;
        const u16x8 xv = *(const u16x8*)(xrow + idx);
        const float4 w1 = *(const float4*)(Wout + idx);
        const float4 w2 = *(const float4*)(Wout + idx + 4);
        acc += bf2f(xv[0]) * w1.x + bf2f(xv[1]) * w1.y + bf2f(xv[2]) * w1.z +
               bf2f(xv[3]) * w1.w + bf2f(xv[4]) * w2.x + bf2f(xv[5]) * w2.y +
               bf2f(xv[6]) * w2.z + bf2f(xv[7]) * w2.w;
    }
#pragma unroll
    for (int off = 32; off; off >>= 1) acc += __shfl_xor(acc, off, 64);
    if (lane == 0) out[m] = acc + bout[0];
}

extern "C" void kernel_launch(void* const* d_in, const int* in_sizes, int n_in,
                              void* d_out, int out_size, void* d_ws, size_t ws_size,
                              hipStream_t stream) {
    const int* item_inputs = (const int*)d_in[0];
    const int* skill_inputs = (const int*)d_in[1];
    const float* emb_item = (const float*)d_in[5];
    const float* emb_skill = (const float*)d_in[6];
    const float* W_in = (const float*)d_in[7];
    const float* b_in = (const float*)d_in[8];
    const float* Wq = (const float*)d_in[9];
    const float* bq = (const float*)d_in[10];
    const float* Wk = (const float*)d_in[11];
    const float* bk = (const float*)d_in[12];
    const float* Wv = (const float*)d_in[13];
    const float* bv = (const float*)d_in[14];
    // d_in[15] Wg, d_in[16] bg: softmax-invariant, skipped.
    const float* pos_key = (const float*)d_in[17];
    const float* Wl = (const float*)d_in[18];
    const float* bl = (const float*)d_in[19];
    const float* W_out = (const float*)d_in[20];
    const float* b_out = (const float*)d_in[21];
    float* out = (float*)d_out;

    const size_t SZ = (size_t)M_ * E_;  // 4M
    __bf16* Xc = (__bf16*)d_ws;         // 8M elems
    __bf16* X = Xc + (size_t)M_ * 2048;
    __bf16* Qb = X + SZ;
    __bf16* Kp = Qb + SZ;               // packed K fragments / MLP scratch
    __bf16* Vp = Kp + SZ;               // packed V fragments
    __bf16* Wall = Vp + SZ;             // 26M elems: 24 layer mats + W_in(2)

    const dim3 gg64(16, 64);            // 64x64 tiles: 1024 blocks
    const dim3 bb(256);

    embed_gather<<<dim3(M_), bb, 0, stream>>>(item_inputs, skill_inputs,
                                              emb_item, emb_skill, Xc);
    cvt_all_weights<<<dim3(EE / 8192, 26), bb, 0, stream>>>(Wq, Wk, Wv, Wl,
                                                            W_in, Wall);

    gemm64<0, 0><<<gg64, bb, 0, stream>>>(Xc, Wall + 24 * (size_t)EE, b_in, X,
                                          2048, nullptr);

    for (int l = 0; l < L_; ++l) {
        __bf16* Wbuf = Wall + (size_t)l * 6 * EE;
        const float* pe_l = pos_key + (size_t)l * S_ * D_;
        gemm64<0, 0><<<gg64, bb, 0, stream>>>(X, Wbuf + 0 * EE, bq + l * E_, Qb, E_, nullptr);
        gemm64<0, 1><<<gg64, bb, 0, stream>>>(Qb, Wbuf + 1 * EE, bk + l * E_, Kp, E_, pe_l);
        gemm64<0, 2><<<gg64, bb, 0, stream>>>(Qb, Wbuf + 2 * EE, bv + l * E_, Vp, E_, nullptr);
        attn_mfma<<<dim3(S_ / 128, B_ * H_), dim3(512), 0, stream>>>(Qb, Kp, Vp, X);
        gemm64<1, 0><<<gg64, bb, 0, stream>>>(X, Wbuf + 3 * EE, bl + (l * 3 + 0) * E_, Qb, E_, nullptr);
        gemm64<1, 0><<<gg64, bb, 0, stream>>>(Qb, Wbuf + 4 * EE, bl + (l * 3 + 1) * E_, Kp, E_, nullptr);
        gemm64<1, 0><<<gg64, bb, 0, stream>>>(Kp, Wbuf + 5 * EE, bl + (l * 3 + 2) * E_, X, E_, nullptr);
    }
    final_proj<<<dim3(M_ / 4), bb, 0, stream>>>(X, W_out, b_out, out);
}

// Round 20
// 544.060 us; speedup vs baseline: 1.0271x; 1.0271x over previous
//
#include <hip/hip_runtime.h>
#include <hip/hip_bf16.h>

// AKT forward, round 20: best-of-measured assembly.
//   cvt: 8 elems/thread, 2-D div-free grid (max block count — best measured)
//   gemm64: BK=128 64x64 tiles, 4/CU (r17/r18, 17us each)
//   attn: KVBLK=64, LDS 32KB (r18, 25us each)
//   - glo term dropped (softmax-invariant per-query constant)
//   - pos_key folded into k-GEMM epilogue
// Workspace (~100 MB): Xc 8M | X,Qb,Kp,Vp 4M | Wall 26M elems

#define B_ 4
#define S_ 1024
#define E_ 1024
#define H_ 16
#define D_ 64
#define L_ 4
#define M_ (B_ * S_)  // 4096
#define EE (E_ * E_)  // 1M

typedef __attribute__((ext_vector_type(8))) __bf16 bf16x8;
typedef __attribute__((ext_vector_type(4))) __bf16 bf16x4;
typedef __attribute__((ext_vector_type(4))) float f32x4;
typedef __attribute__((ext_vector_type(8))) unsigned short u16x8;

__device__ __forceinline__ float bf2f(unsigned short u) {
    union { unsigned int i; float f; } x;
    x.i = ((unsigned int)u) << 16;
    return x.f;
}
__device__ __forceinline__ float gelu_exact(float x) {
    return 0.5f * x * (1.0f + erff(x * 0.70710678118654752f));
}
__device__ __forceinline__ bf16x8 pack8(const float4 a, const float4 b) {
    bf16x8 o;
    o[0] = (__bf16)a.x; o[1] = (__bf16)a.y; o[2] = (__bf16)a.z; o[3] = (__bf16)a.w;
    o[4] = (__bf16)b.x; o[5] = (__bf16)b.y; o[6] = (__bf16)b.z; o[7] = (__bf16)b.w;
    return o;
}

// Packed K layout: frag=((bh*16+kt)*4+kb)*2+kc, elem=lane*8+j.
__device__ __forceinline__ size_t kpack_idx(int m, int col) {
    const int b = m >> 10, srow = m & (S_ - 1);
    const int h = col >> 6, d = col & 63;
    const int bh = b * H_ + h;
    const int kt = srow >> 6, kb = (srow >> 4) & 3, l15 = srow & 15;
    const int kc = d >> 5, lhi = (d >> 3) & 3, j = d & 7;
    const int frag = ((bh * 16 + kt) * 4 + kb) * 2 + kc;
    return (size_t)frag * 512 + (size_t)(lhi * 16 + l15) * 8 + j;
}
// Packed V layout (key-permuted to match P^T B-fragments).
__device__ __forceinline__ size_t vpack_idx(int m, int col) {
    const int b = m >> 10, key = m & (S_ - 1);
    const int h = col >> 6, d = col & 63;
    const int bh = b * H_ + h;
    const int kt = key >> 6;
    const int k6 = key & 63;
    const int kc = k6 >> 5, kl = k6 & 31;
    const int lhi = (kl >> 2) & 3;
    const int j = ((kl >> 4) << 2) | (kl & 3);
    const int db = d >> 4, l15 = d & 15;
    const int frag = ((bh * 16 + kt) * 4 + db) * 2 + kc;
    return (size_t)frag * 512 + (size_t)(lhi * 16 + l15) * 8 + j;
}

// ---------------------------------------------------------------------------
// ALL weights -> bf16, 8 elems/thread, max block count.
// blockIdx.y in [0,26): y<24 -> layer weights; y>=24 -> W_in half.
// ---------------------------------------------------------------------------
__global__ __launch_bounds__(256) void cvt_all_weights(
    const float* __restrict__ Wq, const float* __restrict__ Wk,
    const float* __restrict__ Wv, const float* __restrict__ Wl,
    const float* __restrict__ Win, __bf16* __restrict__ out) {
    const int y = blockIdx.y;  // 0..25
    const int off = (blockIdx.x * 256 + threadIdx.x) * 8;  // < EE
    const float* src;
    if (y >= 24) {
        src = Win + (size_t)(y - 24) * EE + off;
    } else {
        const int l = y / 6, mat = y - l * 6;
        src = (mat == 0) ? Wq + (size_t)l * EE + off
            : (mat == 1) ? Wk + (size_t)l * EE + off
            : (mat == 2) ? Wv + (size_t)l * EE + off
                         : Wl + ((size_t)l * 3 + (mat - 3)) * EE + off;
    }
    const float4 a = *(const float4*)src;
    const float4 b = *(const float4*)(src + 4);
    *(bf16x8*)(out + (size_t)y * EE + off) = pack8(a, b);
}

// ---------------------------------------------------------------------------
// Xc[r, 0:2048] = bf16(concat(emb_item[item_idx[r]], emb_skill[skill_idx[r]]))
// ---------------------------------------------------------------------------
__global__ __launch_bounds__(256) void embed_gather(
    const int* __restrict__ item_idx, const int* __restrict__ skill_idx,
    const float* __restrict__ emb_item, const float* __restrict__ emb_skill,
    __bf16* __restrict__ Xc) {
    const int r = blockIdx.x;
    const int c = threadIdx.x * 8;
    const float* s = (c < E_) ? emb_item + (size_t)item_idx[r] * E_ + c
                              : emb_skill + (size_t)skill_idx[r] * E_ + (c - E_);
    const float4 a = *(const float4*)s;
    const float4 b = *(const float4*)(s + 4);
    *(bf16x8*)(Xc + (size_t)r * 2048 + c) = pack8(a, b);
}

// ---------------------------------------------------------------------------
// 64x64-tile GEMM, BK=128: C = A[M_,K]bf16 * Bm[1024,K]^T + bias.
// PACK: 0 = row-major C (+opt GELU); 1 = K-fragment-pack (+pe); 2 = V-pack.
// Grid (16, 64) = 1024 blocks = 4/CU. LDS 32 KB/block.
// ---------------------------------------------------------------------------
template <int ACT, int PACK>
__global__ __launch_bounds__(256) void gemm64(
    const __bf16* __restrict__ A, const __bf16* __restrict__ Bm,
    const float* __restrict__ bias, __bf16* __restrict__ C, int K,
    const float* __restrict__ pe) {
    __shared__ __bf16 As[64 * 128];  // 16 KB
    __shared__ __bf16 Bs[64 * 128];  // 16 KB
    const int tid = threadIdx.x;
    const int lane = tid & 63;
    const int wid = tid >> 6;
    const int wm = wid >> 1;
    const int wn = wid & 1;
    const int l15 = lane & 15, lhi = lane >> 4;

    const int gx = gridDim.x;  // 16
    const int id = blockIdx.y * gx + blockIdx.x;
    const int nwg = gx * gridDim.y;
    const int swz = (id & 7) * (nwg >> 3) + (id >> 3);
    const int m0 = (swz / gx) * 64;
    const int n0 = (swz % gx) * 64;

    const __bf16* pa[4];
    __bf16* la[4];
    const __bf16* pb[4];
    __bf16* lb[4];
#pragma unroll
    for (int j = 0; j < 4; ++j) {
        const int c = wid * 256 + j * 64 + lane;
        const int row = c >> 4, ch = c & 15;
        pa[j] = A + (size_t)(m0 + row) * K + ((ch ^ (row & 15)) << 3);
        la[j] = As + (size_t)c * 8;
        pb[j] = Bm + (size_t)(n0 + row) * K + ((ch ^ (row & 15)) << 3);
        lb[j] = Bs + (size_t)c * 8;
    }

    int aoff[2][4], boff[2][4];
#pragma unroll
    for (int mi = 0; mi < 2; ++mi) {
        const int row = wm * 32 + mi * 16 + l15;
#pragma unroll
        for (int kc = 0; kc < 4; ++kc)
            aoff[mi][kc] = row * 128 + (((kc * 4 + lhi) ^ (row & 15)) << 3);
    }
#pragma unroll
    for (int ni = 0; ni < 2; ++ni) {
        const int row = wn * 32 + ni * 16 + l15;
#pragma unroll
        for (int kc = 0; kc < 4; ++kc)
            boff[ni][kc] = row * 128 + (((kc * 4 + lhi) ^ (row & 15)) << 3);
    }

    f32x4 acc[2][2] = {};

    for (int k0 = 0; k0 < K; k0 += 128) {
#pragma unroll
        for (int j = 0; j < 4; ++j) {
            __builtin_amdgcn_global_load_lds(
                (const __attribute__((address_space(1))) unsigned int*)(pa[j] + k0),
                (__attribute__((address_space(3))) unsigned int*)la[j], 16, 0, 0);
            __builtin_amdgcn_global_load_lds(
                (const __attribute__((address_space(1))) unsigned int*)(pb[j] + k0),
                (__attribute__((address_space(3))) unsigned int*)lb[j], 16, 0, 0);
        }
        __syncthreads();
        bf16x8 af[2][4], bfr[2][4];
#pragma unroll
        for (int mi = 0; mi < 2; ++mi)
#pragma unroll
            for (int kc = 0; kc < 4; ++kc)
                af[mi][kc] = *(const bf16x8*)(As + aoff[mi][kc]);
#pragma unroll
        for (int ni = 0; ni < 2; ++ni)
#pragma unroll
            for (int kc = 0; kc < 4; ++kc)
                bfr[ni][kc] = *(const bf16x8*)(Bs + boff[ni][kc]);
#pragma unroll
        for (int mi = 0; mi < 2; ++mi)
#pragma unroll
            for (int ni = 0; ni < 2; ++ni)
#pragma unroll
                for (int kc = 0; kc < 4; ++kc)
                    acc[mi][ni] = __builtin_amdgcn_mfma_f32_16x16x32_bf16(
                        af[mi][kc], bfr[ni][kc], acc[mi][ni], 0, 0, 0);
        __syncthreads();
    }

    const int ccol0 = n0 + wn * 32 + l15;
    const int crow0 = m0 + wm * 32 + (lhi << 2);
#pragma unroll
    for (int mi = 0; mi < 2; ++mi) {
#pragma unroll
        for (int ni = 0; ni < 2; ++ni) {
            const int col = ccol0 + ni * 16;
            const float bsum = bias[col];
#pragma unroll
            for (int r = 0; r < 4; ++r) {
                const int row = crow0 + mi * 16 + r;
                float v = acc[mi][ni][r] + bsum;
                if (PACK == 0) {
                    if (ACT) v = gelu_exact(v);
                    C[(size_t)row * E_ + col] = (__bf16)v;
                } else if (PACK == 1) {
                    v += pe[((row & (S_ - 1)) << 6) + (col & (D_ - 1))];
                    C[kpack_idx(row, col)] = (__bf16)v;
                } else {
                    C[vpack_idx(row, col)] = (__bf16)v;
                }
            }
        }
    }
}

// ---------------------------------------------------------------------------
// Swapped-QK MFMA flash attention, KVBLK=64, LDS-staged K/V, 8 waves.
// ---------------------------------------------------------------------------
__global__ __launch_bounds__(512) void attn_mfma(
    const __bf16* __restrict__ Q, const __bf16* __restrict__ Kp,
    const __bf16* __restrict__ Vp, __bf16* __restrict__ O) {
    __shared__ __bf16 Slds[2][2][8 * 512];  // 32 KB
    const int tid = threadIdx.x;
    const int lane = tid & 63;
    const int w = tid >> 6;
    const int l15 = lane & 15, lhi = lane >> 4;

    const int id = blockIdx.y * gridDim.x + blockIdx.x;  // 0..511
    const int swz = (id & 7) * 64 + (id >> 3);
    const int q0 = (swz & 7) * 128 + w * 16;
    const int bh = swz >> 3;
    const int bb = bh >> 4, hh = bh & 15;

    bf16x8 qf[2];
    {
        const __bf16* qrow =
            Q + (size_t)(bb * S_ + q0 + l15) * E_ + hh * 64 + lhi * 8;
#pragma unroll
        for (int kc = 0; kc < 2; ++kc) {
            const u16x8 raw = *(const u16x8*)(qrow + kc * 32);
            bf16x8 v;
#pragma unroll
            for (int j = 0; j < 8; ++j) v[j] = (__bf16)(bf2f(raw[j]) * 0.125f);
            qf[kc] = v;
        }
    }

    const __bf16* kpw = Kp + ((size_t)bh * 16 * 8 + w) * 512 + lane * 8;
    const __bf16* vpw = Vp + ((size_t)bh * 16 * 8 + w) * 512 + lane * 8;

    float m_l = -1e30f, l_l = 0.f;
    f32x4 oacc[4] = {};

    __builtin_amdgcn_global_load_lds(
        (const __attribute__((address_space(1))) unsigned int*)(kpw),
        (__attribute__((address_space(3))) unsigned int*)(&Slds[0][0][w * 512]),
        16, 0, 0);
    __builtin_amdgcn_global_load_lds(
        (const __attribute__((address_space(1))) unsigned int*)(vpw),
        (__attribute__((address_space(3))) unsigned int*)(&Slds[0][1][w * 512]),
        16, 0, 0);

#pragma unroll 2
    for (int kt = 0; kt < S_ / 64; ++kt) {
        const int cur = kt & 1;
        __syncthreads();
        if (kt < S_ / 64 - 1) {
            const size_t fo = (size_t)(kt + 1) * 8 * 512;
            __builtin_amdgcn_global_load_lds(
                (const __attribute__((address_space(1))) unsigned int*)(kpw + fo),
                (__attribute__((address_space(3))) unsigned int*)(
                    &Slds[cur ^ 1][0][w * 512]), 16, 0, 0);
            __builtin_amdgcn_global_load_lds(
                (const __attribute__((address_space(1))) unsigned int*)(vpw + fo),
                (__attribute__((address_space(3))) unsigned int*)(
                    &Slds[cur ^ 1][1][w * 512]), 16, 0, 0);
        }
        const __bf16* kl = &Slds[cur][0][0];
        const __bf16* vl = &Slds[cur][1][0];
        f32x4 s[4];
#pragma unroll
        for (int kb = 0; kb < 4; ++kb) {
            const bf16x8 k0 = *(const bf16x8*)(kl + (kb * 2 + 0) * 512 + lane * 8);
            const bf16x8 k1 = *(const bf16x8*)(kl + (kb * 2 + 1) * 512 + lane * 8);
            f32x4 z = {};
            z = __builtin_amdgcn_mfma_f32_16x16x32_bf16(k0, qf[0], z, 0, 0, 0);
            s[kb] = __builtin_amdgcn_mfma_f32_16x16x32_bf16(k1, qf[1], z, 0, 0, 0);
        }
        float mx0 = fmaxf(fmaxf(s[0][0], s[0][1]), fmaxf(s[0][2], s[0][3]));
        float mx1 = fmaxf(fmaxf(s[1][0], s[1][1]), fmaxf(s[1][2], s[1][3]));
        float mx2 = fmaxf(fmaxf(s[2][0], s[2][1]), fmaxf(s[2][2], s[2][3]));
        float mx3 = fmaxf(fmaxf(s[3][0], s[3][1]), fmaxf(s[3][2], s[3][3]));
        float mx = fmaxf(fmaxf(mx0, mx1), fmaxf(mx2, mx3));
        mx = fmaxf(mx, __shfl_xor(mx, 16));
        mx = fmaxf(mx, __shfl_xor(mx, 32));
        const float mnew = fmaxf(m_l, mx);
        const float corr = __expf(m_l - mnew);
        float p[4][4];
        float rs = 0.f;
#pragma unroll
        for (int kb = 0; kb < 4; ++kb) {
            float sb = 0.f;
#pragma unroll
            for (int r = 0; r < 4; ++r) {
                p[kb][r] = __expf(s[kb][r] - mnew);
                sb += p[kb][r];
            }
            rs += sb;
        }
        rs += __shfl_xor(rs, 16);
        rs += __shfl_xor(rs, 32);
        l_l = l_l * corr + rs;
        m_l = mnew;
#pragma unroll
        for (int db = 0; db < 4; ++db)
#pragma unroll
            for (int r = 0; r < 4; ++r) oacc[db][r] *= corr;
        bf16x8 pf[2];
#pragma unroll
        for (int kc = 0; kc < 2; ++kc) {
            bf16x8 v;
#pragma unroll
            for (int r = 0; r < 4; ++r) {
                v[r] = (__bf16)p[kc * 2][r];
                v[r + 4] = (__bf16)p[kc * 2 + 1][r];
            }
            pf[kc] = v;
        }
#pragma unroll
        for (int db = 0; db < 4; ++db) {
            const bf16x8 v0 = *(const bf16x8*)(vl + (db * 2 + 0) * 512 + lane * 8);
            const bf16x8 v1 = *(const bf16x8*)(vl + (db * 2 + 1) * 512 + lane * 8);
            oacc[db] = __builtin_amdgcn_mfma_f32_16x16x32_bf16(v0, pf[0], oacc[db], 0, 0, 0);
            oacc[db] = __builtin_amdgcn_mfma_f32_16x16x32_bf16(v1, pf[1], oacc[db], 0, 0, 0);
        }
    }
    const float inv_l = 1.f / l_l;
    __bf16* orow = O + (size_t)(bb * S_ + q0 + l15) * E_ + hh * 64 + lhi * 4;
#pragma unroll
    for (int db = 0; db < 4; ++db) {
        bf16x4 ov;
#pragma unroll
        for (int r = 0; r < 4; ++r) ov[r] = (__bf16)(oacc[db][r] * inv_l);
        *(bf16x4*)(orow + db * 16) = ov;
    }
}

// ---------------------------------------------------------------------------
// out[m] = bf16 x[m,:] . f32 W_out + b_out -> f32. One wave per row.
// ---------------------------------------------------------------------------
__global__ __launch_bounds__(256) void final_proj(
    const __bf16* __restrict__ X, const float* __restrict__ Wout,
    const float* __restrict__ bout, float* __restrict__ out) {
    const int wid = threadIdx.x >> 6, lane = threadIdx.x & 63;
    const int m = blockIdx.x * 4 + wid;
    const __bf16* xrow = X + (size_t)m * E_;
    float acc = 0.f;
#pragma unroll
    for (int c = 0; c < 2; ++c) {
        const int idx = c * 512 + lane * 8;
        const u16x8 xv = *(const u16x8*)(xrow + idx);
        const float4 w1 = *(const float4*)(Wout + idx);
        const float4 w2 = *(const float4*)(Wout + idx + 4);
        acc += bf2f(xv[0]) * w1.x + bf2f(xv[1]) * w1.y + bf2f(xv[2]) * w1.z +
               bf2f(xv[3]) * w1.w + bf2f(xv[4]) * w2.x + bf2f(xv[5]) * w2.y +
               bf2f(xv[6]) * w2.z + bf2f(xv[7]) * w2.w;
    }
#pragma unroll
    for (int off = 32; off; off >>= 1) acc += __shfl_xor(acc, off, 64);
    if (lane == 0) out[m] = acc + bout[0];
}

extern "C" void kernel_launch(void* const* d_in, const int* in_sizes, int n_in,
                              void* d_out, int out_size, void* d_ws, size_t ws_size,
                              hipStream_t stream) {
    const int* item_inputs = (const int*)d_in[0];
    const int* skill_inputs = (const int*)d_in[1];
    const float* emb_item = (const float*)d_in[5];
    const float* emb_skill = (const float*)d_in[6];
    const float* W_in = (const float*)d_in[7];
    const float* b_in = (const float*)d_in[8];
    const float* Wq = (const float*)d_in[9];
    const float* bq = (const float*)d_in[10];
    const float* Wk = (const float*)d_in[11];
    const float* bk = (const float*)d_in[12];
    const float* Wv = (const float*)d_in[13];
    const float* bv = (const float*)d_in[14];
    // d_in[15] Wg, d_in[16] bg: softmax-invariant, skipped.
    const float* pos_key = (const float*)d_in[17];
    const float* Wl = (const float*)d_in[18];
    const float* bl = (const float*)d_in[19];
    const float* W_out = (const float*)d_in[20];
    const float* b_out = (const float*)d_in[21];
    float* out = (float*)d_out;

    const size_t SZ = (size_t)M_ * E_;  // 4M
    __bf16* Xc = (__bf16*)d_ws;         // 8M elems
    __bf16* X = Xc + (size_t)M_ * 2048;
    __bf16* Qb = X + SZ;
    __bf16* Kp = Qb + SZ;               // packed K fragments / MLP scratch
    __bf16* Vp = Kp + SZ;               // packed V fragments
    __bf16* Wall = Vp + SZ;             // 26M elems: 24 layer mats + W_in(2)

    const dim3 gg64(16, 64);            // 64x64 tiles: 1024 blocks
    const dim3 bb(256);

    embed_gather<<<dim3(M_), bb, 0, stream>>>(item_inputs, skill_inputs,
                                              emb_item, emb_skill, Xc);
    cvt_all_weights<<<dim3(EE / 2048, 26), bb, 0, stream>>>(Wq, Wk, Wv, Wl,
                                                            W_in, Wall);

    gemm64<0, 0><<<gg64, bb, 0, stream>>>(Xc, Wall + 24 * (size_t)EE, b_in, X,
                                          2048, nullptr);

    for (int l = 0; l < L_; ++l) {
        __bf16* Wbuf = Wall + (size_t)l * 6 * EE;
        const float* pe_l = pos_key + (size_t)l * S_ * D_;
        gemm64<0, 0><<<gg64, bb, 0, stream>>>(X, Wbuf + 0 * EE, bq + l * E_, Qb, E_, nullptr);
        gemm64<0, 1><<<gg64, bb, 0, stream>>>(Qb, Wbuf + 1 * EE, bk + l * E_, Kp, E_, pe_l);
        gemm64<0, 2><<<gg64, bb, 0, stream>>>(Qb, Wbuf + 2 * EE, bv + l * E_, Vp, E_, nullptr);
        attn_mfma<<<dim3(S_ / 128, B_ * H_), dim3(512), 0, stream>>>(Qb, Kp, Vp, X);
        gemm64<1, 0><<<gg64, bb, 0, stream>>>(X, Wbuf + 3 * EE, bl + (l * 3 + 0) * E_, Qb, E_, nullptr);
        gemm64<1, 0><<<gg64, bb, 0, stream>>>(Qb, Wbuf + 4 * EE, bl + (l * 3 + 1) * E_, Kp, E_, nullptr);
        gemm64<1, 0><<<gg64, bb, 0, stream>>>(Kp, Wbuf + 5 * EE, bl + (l * 3 + 2) * E_, X, E_, nullptr);
    }
    final_proj<<<dim3(M_ / 4), bb, 0, stream>>>(X, W_out, b_out, out);
}